// Round 12
// baseline (416.615 us; speedup 1.0000x reference)
//
#include <hip/hip_runtime.h>
#include <hip/hip_bf16.h>
#include <cstdint>

using bf16 = __hip_bfloat16;
typedef __attribute__((ext_vector_type(8))) short bf16x8;
typedef __attribute__((ext_vector_type(16))) float f32x16;

struct alignas(16) B8 { bf16 h[8]; };
struct alignas(8)  B4 { bf16 h[4]; };

__device__ __forceinline__ void gll16(const void* g, void* l) {
  __builtin_amdgcn_global_load_lds((__attribute__((address_space(1))) void*)g,
                                   (__attribute__((address_space(3))) void*)l,
                                   16, 0, 0);
}

// =================================================================================
// FRAGMENT-MAJOR GLOBAL LAYOUT v2 (32x32x16 MFMA): for a [rows][1024] operand,
// 16-B chunk id = ((row>>5)*64 + (k>>4))*64 + ((k>>3)&1)*32 + (row&31),
// chunk content = 8 bf16 k-elems. One MFMA fragment (32 rows x 16 k) = 64
// consecutive chunks = 1KB: gll16 stages exactly one frag contiguously; frag
// ds_read_b128 = base + lane*16 (lane l -> row l&31, k-half l>>5) -> zero
// bank conflicts, perfect global coalescing.
// =================================================================================

// ---------------- x fp32 [32768][1024] -> fragment-major-v2 bf16 ----------------
__global__ __launch_bounds__(256) void cast_x_frag(const float* __restrict__ x,
                                                   bf16* __restrict__ xr) {
  __shared__ float tile[32][257];
  const int g = blockIdx.x;                    // 32-row group, 0..1023
  const int t = threadIdx.x;
  const float* src = x + (size_t)g * 32768;    // 32 rows * 1024
  bf16* dst = xr + (size_t)g * 32768;
  for (int kp = 0; kp < 4; ++kp) {
    const int k0 = kp * 256;
    if (kp) __syncthreads();
    {
      const int r = t >> 4, cl = t & 15;       // lanes 0..15 read 64B contiguous
      #pragma unroll
      for (int hh = 0; hh < 2; ++hh)
        #pragma unroll
        for (int s = 0; s < 16; ++s)
          tile[hh * 16 + r][cl + 16 * s] =
              src[(size_t)(hh * 16 + r) * 1024 + k0 + cl + 16 * s];
    }
    __syncthreads();
    #pragma unroll
    for (int rd = 0; rd < 4; ++rd) {
      const int c = rd * 256 + t;              // chunk within panel, 0..1023
      const int row = c & 31, sh = (c >> 5) & 1, kb = c >> 6;
      B8 o;
      #pragma unroll
      for (int jj = 0; jj < 8; ++jj)
        o.h[jj] = __float2bfloat16(tile[row][kb * 16 + sh * 8 + jj]);
      *(B8*)(dst + ((size_t)kp * 1024 + c) * 8) = o;   // contiguous stores
    }
  }
}

// ---------------- W fp32 [K][N] -> fragment-major-v2 bf16 of W^T ----------------
__global__ __launch_bounds__(256) void wcast_frag(const float* __restrict__ W,
                                                  bf16* __restrict__ out,
                                                  int N, int n_glob0) {
  __shared__ float tw[256][33];
  const int k0 = blockIdx.x * 256;
  const int n0 = blockIdx.y * 32;
  const int t = threadIdx.x;
  {
    const int nn = t & 31, kk = t >> 5;        // lanes 0..31: 128B contiguous
    #pragma unroll
    for (int s = 0; s < 32; ++s)
      tw[kk + 8 * s][nn] = W[(size_t)(k0 + kk + 8 * s) * N + n0 + nn];
  }
  __syncthreads();
  const size_t ng = (size_t)((n_glob0 + n0) >> 5);
  #pragma unroll
  for (int rd = 0; rd < 4; ++rd) {
    const int c = rd * 256 + t;
    const int nn = c & 31, sh = (c >> 5) & 1, kb = c >> 6;
    B8 o;
    #pragma unroll
    for (int jj = 0; jj < 8; ++jj)
      o.h[jj] = __float2bfloat16(tw[kb * 16 + sh * 8 + jj][nn]);
    *(B8*)(out + ((ng * 64 + (k0 >> 4) + kb) * 64 + sh * 32 + nn) * 8) = o;
  }
}

// ---------------- transpose + cast: W[K][N] fp32 -> WT[N][K] bf16 (row-major) ----
__global__ void tcast(const float* __restrict__ W, bf16* __restrict__ WT, int K, int N) {
  __shared__ float tile[32][33];
  int k0 = blockIdx.y * 32, n0 = blockIdx.x * 32;
  int tx = threadIdx.x, ty = threadIdx.y;  // block (32,8)
  for (int yy = ty; yy < 32; yy += 8)
    tile[yy][tx] = W[(size_t)(k0 + yy) * N + n0 + tx];
  __syncthreads();
  for (int yy = ty; yy < 32; yy += 8)
    WT[(size_t)(n0 + yy) * K + k0 + tx] = __float2bfloat16(tile[tx][yy]);
}

// =================================================================================
// 256x256-tile, BK=32/section, 8-wave main loop — 32x32x16 MFMA variant (r12).
// Same r8 ring schedule (4 slots/operand, staged 3 ahead, 4 gll16/section/wave
// -> identical vmcnt(4) accounting, boundary = vmcnt(4)+s_barrier). Per section
// per wave: 16 MFMA (was 32 of 16x16x32 — same FLOPs, ~15% higher pipe ceiling
// per m119: 2495 vs 2176 TF), 12 ds_read_b128, 4 gll16 interleaved in-cluster.
// Wave tile 128x64 = 4 row-tiles x 2 col-tiles of 32x32; acc = 8 x f32x16.
// =================================================================================
__device__ __forceinline__ void gemm_mainloop_256(
    const bf16* __restrict__ aop, const bf16* __restrict__ bop,
    bf16* ldsA, bf16* ldsB, int wd, int aoff, int boff, f32x16 (&acc)[4][2])
{
#define SFULL(slot, ko) do { \
    gll16(aop + (ko) * 32,       ldsA + (slot) * 8192 + wd); \
    gll16(aop + (ko) * 32 + 512, ldsA + (slot) * 8192 + wd + 512); \
    gll16(bop + (ko) * 32,       ldsB + (slot) * 8192 + wd); \
    gll16(bop + (ko) * 32 + 512, ldsB + (slot) * 8192 + wd + 512); } while (0)
#define AFRAG(slot, i, kb) (*(const bf16x8*)(ldsA + (slot) * 8192 + aoff + ((i) * 2 + (kb)) * 512))
#define BFRAG(slot, j, kb) (*(const bf16x8*)(ldsB + (slot) * 8192 + boff + ((j) * 2 + (kb)) * 512))

  bf16x8 a1[4], a2[4], b1[2], b2[2];

#define SECTION(S, DO_PF, PFS, DO_ST, SLOT, KO)                                     \
  do {                                                                              \
    asm volatile("s_waitcnt lgkmcnt(0)" ::: "memory");                              \
    __builtin_amdgcn_sched_barrier(0);                                              \
    __builtin_amdgcn_s_setprio(1);                                                  \
    _Pragma("unroll")                                                               \
    for (int i = 0; i < 4; i++) {                                                   \
      acc[i][0] = __builtin_amdgcn_mfma_f32_32x32x16_bf16(a1[i], b1[0], acc[i][0], 0, 0, 0); \
      acc[i][1] = __builtin_amdgcn_mfma_f32_32x32x16_bf16(a1[i], b1[1], acc[i][1], 0, 0, 0); \
      a2[i] = AFRAG(S, i, 1);                                                       \
      if (i == 0) b2[0] = BFRAG(S, 0, 1);                                           \
      if (i == 1) b2[1] = BFRAG(S, 1, 1);                                           \
      if (DO_ST && i == 2) gll16(aop + (KO) * 32, ldsA + (SLOT) * 8192 + wd);       \
      if (DO_ST && i == 3) gll16(aop + (KO) * 32 + 512, ldsA + (SLOT) * 8192 + wd + 512); \
    }                                                                               \
    asm volatile("s_waitcnt lgkmcnt(0)" ::: "memory");                              \
    __builtin_amdgcn_sched_barrier(0);                                              \
    _Pragma("unroll")                                                               \
    for (int i = 0; i < 4; i++) {                                                   \
      acc[i][0] = __builtin_amdgcn_mfma_f32_32x32x16_bf16(a2[i], b2[0], acc[i][0], 0, 0, 0); \
      acc[i][1] = __builtin_amdgcn_mfma_f32_32x32x16_bf16(a2[i], b2[1], acc[i][1], 0, 0, 0); \
      if (DO_PF) {                                                                  \
        a1[i] = AFRAG(PFS, i, 0);                                                   \
        if (i == 0) b1[0] = BFRAG(PFS, 0, 0);                                       \
        if (i == 1) b1[1] = BFRAG(PFS, 1, 0);                                       \
      }                                                                             \
      if (DO_ST && i == 2) gll16(bop + (KO) * 32, ldsB + (SLOT) * 8192 + wd);       \
      if (DO_ST && i == 3) gll16(bop + (KO) * 32 + 512, ldsB + (SLOT) * 8192 + wd + 512); \
    }                                                                               \
    __builtin_amdgcn_s_setprio(0);                                                  \
  } while (0)

#define BOUNDARY(VMC)                                                               \
  do {                                                                              \
    asm volatile("s_waitcnt vmcnt(" #VMC ")" ::: "memory");                         \
    __builtin_amdgcn_s_barrier();                                                   \
    __builtin_amdgcn_sched_barrier(0);                                              \
  } while (0)

  // prologue: stage slots 0,1,2 (12 gll16); retire 0,1; slot 2 stays in flight
  SFULL(0, 0); SFULL(1, 32); SFULL(2, 64);
  asm volatile("s_waitcnt vmcnt(4)" ::: "memory");
  __builtin_amdgcn_s_barrier();
  __builtin_amdgcn_sched_barrier(0);
  b1[0] = BFRAG(0, 0, 0); b1[1] = BFRAG(0, 1, 0);
  #pragma unroll
  for (int i = 0; i < 4; i++) a1[i] = AFRAG(0, i, 0);

  // sections 0..27: section v consumes slot v&3, prefetches (v+1)&3,
  // stages slot (v+3)&3 at ko=(v+3)*32 inside its MFMA clusters.
  for (int q = 0; q < 7; ++q) {
    const int ko = q * 128;
    SECTION(0, true, 1, true, 3, ko + 96);
    BOUNDARY(4);
    SECTION(1, true, 2, true, 0, ko + 128);
    BOUNDARY(4);
    SECTION(2, true, 3, true, 1, ko + 160);
    BOUNDARY(4);
    SECTION(3, true, 0, true, 2, ko + 192);
    BOUNDARY(4);
  }
  // tail: v=28 (stages last chunk ko=992 -> slot 3), then drain
  SECTION(0, true, 1, true, 3, 992);
  BOUNDARY(4);
  SECTION(1, true, 2, false, 0, 0);
  BOUNDARY(0);
  SECTION(2, true, 3, false, 0, 0);
  BOUNDARY(0);
  SECTION(3, false, 0, false, 0, 0);

  __syncthreads();   // all frag reads done before epilogues reuse/overwrite LDS
#undef SECTION
#undef BOUNDARY
#undef SFULL
#undef AFRAG
#undef BFRAG
}

// =================================================================================
// Fused QKV GEMM:  T = x_bf @ [Wq | Wkv]  (M=32768, N=3072, K=1024)
//  - 32x32 C/D layout (verified m74/m101): col=lane&31, row=(reg&3)+8*(reg>>2)
//    +4*(lane>>5). Wave tile 128x64: row-tile i (32 rows), col-tile j (32 cols).
//  - q tiles (bn<4): wave's 64 cols = one head; per-row softmax (each row lives
//    in one 32-lane half, 1 reg per j-tile) -> 5-stage shfl reduce; Yq frag-v2.
//  - kv tiles: 2 heads/block; exp(k)/v -> LDS as 32x32x16 MFMA operands
//    ([kb(16)][Dgrp(2)] frag-major, B4 writes per reg-quad); Z register-resident;
//    R via 16 x mfma_32x32x16 per wave (wave = head x (D,E) tile); fp32 atomics.
// =================================================================================
constexpr int QKV_NT = 12;   // N/256

__global__ __launch_bounds__(512, 2)
void gemm_qkv(const bf16* __restrict__ A, const bf16* __restrict__ BT,
              bf16* __restrict__ Yq, float* __restrict__ ctxAcc)
{
  __shared__ __align__(16) union {
    struct { bf16 a[4 * 8192]; bf16 b[4 * 8192]; } g;       // 4+4 slots (16KB each)
    struct { bf16 ekT[2][16384]; bf16 vT[2][16384]; } c;    // kv epilogue (frag-major)
  } sm;

  const int t = threadIdx.x;
  const int wave = t >> 6, lane = t & 63;
  const int ln = lane & 31, hi = lane >> 5;
  const int wm = wave >> 2, wn = wave & 3;
  // XCD-chunked swizzle (bijective: 1536 = 8 * 192; dispatch round-robins bid%8)
  const int bid = (int)blockIdx.x;
  const int swz = (bid & 7) * 192 + (bid >> 3);
  const int bm = swz / QKV_NT, bn = swz % QKV_NT;
  const int m0 = bm * 256, n0 = bn * 256;

  // staging: wave stages 32-row group (m0>>5)+wave; lane sources chunk base+lane
  const bf16* aop = A + (size_t)((m0 >> 5) + wave) * 32768 + lane * 8;
  const bf16* bop = BT + (size_t)((n0 >> 5) + wave) * 32768 + lane * 8;
  const int wd = wave * 1024;          // elems; gll16 writes base + lane*16B
  const int aoff = wm * 4096 + lane * 8;   // + (i*2+kb)*512 per frag
  const int boff = wn * 2048 + lane * 8;   // + (j*2+kb)*512 per frag

  f32x16 acc[4][2];
  #pragma unroll
  for (int i = 0; i < 4; i++)
    #pragma unroll
    for (int j = 0; j < 2; j++)
      #pragma unroll
      for (int e = 0; e < 16; e++) acc[i][j][e] = 0.f;

  gemm_mainloop_256(aop, bop, sm.g.a, sm.g.b, wd, aoff, boff, acc);

  if (bn < 4) {
    // ---- fused q softmax; Yq written fragment-major v2 ----
    int cp[2];
    #pragma unroll
    for (int j = 0; j < 2; j++) {
      const int c = n0 + wn * 64 + j * 32 + ln;
      cp[j] = ((c >> 4) * 64 + ((c >> 3) & 1) * 32) * 8 + (c & 7);
    }
    #pragma unroll
    for (int i = 0; i < 4; i++) {
      #pragma unroll
      for (int rg = 0; rg < 16; ++rg) {
        const float v0 = acc[i][0][rg], v1 = acc[i][1][rg];
        float m = fmaxf(v0, v1);
        m = fmaxf(m, __shfl_xor(m, 1));
        m = fmaxf(m, __shfl_xor(m, 2));
        m = fmaxf(m, __shfl_xor(m, 4));
        m = fmaxf(m, __shfl_xor(m, 8));
        m = fmaxf(m, __shfl_xor(m, 16));
        const float e0 = __expf(v0 - m), e1 = __expf(v1 - m);
        float s = e0 + e1;
        s += __shfl_xor(s, 1);
        s += __shfl_xor(s, 2);
        s += __shfl_xor(s, 4);
        s += __shfl_xor(s, 8);
        s += __shfl_xor(s, 16);
        const float inv = 0.125f / s;           // scale = DH^-0.5
        const int row = m0 + wm * 128 + i * 32 + (rg & 3) + 8 * (rg >> 2) + 4 * hi;
        const size_t rp = ((size_t)(row >> 5) * 4096 + (row & 31)) * 8;
        Yq[rp + cp[0]] = __float2bfloat16(e0 * inv);
        Yq[rp + cp[1]] = __float2bfloat16(e1 * inv);
      }
    }
  } else {
    // ---- fused context: tile = 256 s-rows x 2 heads (each head: 64 k | 64 v) ----
    const int bb2 = m0 >> 12;                 // batch (4096 rows per batch)
    const int h0 = (n0 - 1024) >> 7;          // first head of this tile
    const int hloc = wn >> 1, isV = wn & 1;   // wave role
    bf16* const dstT = (isV ? sm.c.vT[hloc] : sm.c.ekT[hloc]);

    float zp[2] = {0.f, 0.f};
    #pragma unroll
    for (int i = 0; i < 4; i++) {
      #pragma unroll
      for (int j = 0; j < 2; j++) {
        // ekT[d][s] frag-major: byte = ((s>>4)*2 + (d>>5))*1024 + ((s>>3)&1)*512
        //                              + (d&31)*16 + (s&7)*2;  d = j*32+ln.
        char* base = (char*)dstT + ((wm * 8 + i * 2) * 2 + j) * 1024 + ln * 16 + hi * 8;
        #pragma unroll
        for (int q = 0; q < 4; ++q) {
          B4 pk;
          #pragma unroll
          for (int r = 0; r < 4; ++r) {
            const float v = acc[i][j][q * 4 + r];
            if (!isV) {
              const float e = __expf(v);
              zp[j] += e;
              pk.h[r] = __float2bfloat16(e);
            } else {
              pk.h[r] = __float2bfloat16(v);
            }
          }
          *(B4*)(base + (q >> 1) * 2048 + (q & 1) * 512) = pk;
        }
      }
    }

    if (!isV) {
      // Z[d] partial over this wave's 128 s-rows, straight from registers
      zp[0] += __shfl_xor(zp[0], 32);
      zp[1] += __shfl_xor(zp[1], 32);
      if (hi == 0) {
        float* zb = ctxAcc + (size_t)(bb2 * 16 + h0 + hloc) * 4160 + 4096;
        atomicAdd(zb + ln, zp[0]);
        atomicAdd(zb + 32 + ln, zp[1]);
      }
    }
    __syncthreads();

    // R[d][e] partial: wave -> (head = wave>>2, D = (wave>>1)&1, E = wave&1);
    // K = 256 s-rows = 16 x mfma_32x32x16.
    const int hh = wave >> 2, D = (wave >> 1) & 1, E = wave & 1;
    const char* ek = (const char*)sm.c.ekT[hh];
    const char* vv = (const char*)sm.c.vT[hh];
    f32x16 racc;
    #pragma unroll
    for (int e = 0; e < 16; e++) racc[e] = 0.f;
    #pragma unroll
    for (int kb = 0; kb < 16; ++kb) {
      bf16x8 af  = *(const bf16x8*)(ek + (kb * 2 + D) * 1024 + lane * 16);
      bf16x8 bfr = *(const bf16x8*)(vv + (kb * 2 + E) * 1024 + lane * 16);
      racc = __builtin_amdgcn_mfma_f32_32x32x16_bf16(af, bfr, racc, 0, 0, 0);
    }
    float* cb = ctxAcc + (size_t)(bb2 * 16 + h0 + hh) * 4160;
    #pragma unroll
    for (int rg = 0; rg < 16; ++rg) {
      const int d = D * 32 + (rg & 3) + 8 * (rg >> 2) + 4 * hi;
      atomicAdd(cb + d * 64 + E * 32 + ln, racc[rg]);
    }
  }
}

// ---------------- W2T[b] = (R/Z) @ WlinT-slice, written FRAGMENT-MAJOR v2 --------
__global__ __launch_bounds__(256) void make_w2t(const float* __restrict__ ctxAcc,
                                                const bf16* __restrict__ WlinT,
                                                bf16* __restrict__ W2T) {
  const int nc = blockIdx.x;      // 0..15
  const int bh = blockIdx.y;      // 0..127
  const int b = bh >> 4, h = bh & 15;
  const int t = threadIdx.x, lane = t & 63, w = t >> 6;
  const float* src = ctxAcc + (size_t)bh * 4160;
  const float invz = 1.0f / src[4096 + lane];   // Z[d], d = lane
  float creg[64];
  const float* crow = src + lane * 64;
  #pragma unroll
  for (int e4 = 0; e4 < 16; e4++) {
    float4 v = *(const float4*)(crow + e4 * 4);
    creg[e4 * 4 + 0] = v.x * invz; creg[e4 * 4 + 1] = v.y * invz;
    creg[e4 * 4 + 2] = v.z * invz; creg[e4 * 4 + 3] = v.w * invz;
  }
  for (int i = 0; i < 16; i++) {
    const int n = nc * 64 + w * 16 + i;
    const bf16* wrow = WlinT + (size_t)n * 1024 + h * 64;
    float acc = 0.f;
    #pragma unroll
    for (int e8 = 0; e8 < 8; e8++) {
      B8 v = *(const B8*)(wrow + e8 * 8);
      #pragma unroll
      for (int j = 0; j < 8; j++) acc += creg[e8 * 8 + j] * __bfloat162float(v.h[j]);
    }
    // frag-major v2: k = h*64+lane
    W2T[(size_t)b * 1048576 +
        (((size_t)(n >> 5) * 64 + h * 4 + (lane >> 4)) * 64 + ((lane >> 3) & 1) * 32 + (n & 31)) * 8
        + (lane & 7)] = __float2bfloat16(acc);
  }
}

// ---------------- out[b] = Yq[b] @ W2T[b]^T + blin, fp32 output -------------------
// per batch: M=4096, N=1024, K=1024; fragment-major-v2 operands; grid 512
// XCD-chunked swizzle: each XCD owns one batch (W2T[b] 2MB L2-resident).
__global__ __launch_bounds__(512, 2)
void gemm_out(const bf16* __restrict__ Aall, const bf16* __restrict__ BTall,
              float* __restrict__ Call, const float* __restrict__ bias)
{
  __shared__ __align__(16) struct { bf16 a[4 * 8192]; bf16 b[4 * 8192]; } sm;
  const int t = threadIdx.x;
  const int wave = t >> 6, lane = t & 63;
  const int ln = lane & 31, hi = lane >> 5;
  const int wm = wave >> 2, wn = wave & 3;
  // bijective XCD swizzle: 512 = 8 * 64; XCD x -> batch x
  const int bid = (int)blockIdx.x;
  const int swz = (bid & 7) * 64 + (bid >> 3);
  const int bz = swz >> 6;
  const int r  = swz & 63;
  const int bm = r >> 2, bn = r & 3;
  const int m0 = bm * 256, n0 = bn * 256;
  const bf16* A  = Aall  + (size_t)bz * 4194304;
  const bf16* BT = BTall + (size_t)bz * 1048576;
  float* C       = Call  + (size_t)bz * 4194304;

  const bf16* aop = A + (size_t)((m0 >> 5) + wave) * 32768 + lane * 8;
  const bf16* bop = BT + (size_t)((n0 >> 5) + wave) * 32768 + lane * 8;
  const int wd = wave * 1024;
  const int aoff = wm * 4096 + lane * 8;
  const int boff = wn * 2048 + lane * 8;

  f32x16 acc[4][2];
  #pragma unroll
  for (int i = 0; i < 4; i++)
    #pragma unroll
    for (int j = 0; j < 2; j++)
      #pragma unroll
      for (int e = 0; e < 16; e++) acc[i][j][e] = 0.f;

  gemm_mainloop_256(aop, bop, sm.a, sm.b, wd, aoff, boff, acc);

  float bv[2];
  #pragma unroll
  for (int j = 0; j < 2; j++) bv[j] = bias[n0 + wn * 64 + j * 32 + ln];
  const int col0 = n0 + wn * 64 + ln;
  #pragma unroll
  for (int i = 0; i < 4; i++) {
    #pragma unroll
    for (int rg = 0; rg < 16; ++rg) {
      const int row = m0 + wm * 128 + i * 32 + (rg & 3) + 8 * (rg >> 2) + 4 * hi;
      C[(size_t)row * 1024 + col0]      = acc[i][0][rg] + bv[0];
      C[(size_t)row * 1024 + col0 + 32] = acc[i][1][rg] + bv[1];
    }
  }
}

// ---------------------------------------------------------------------------------
extern "C" void kernel_launch(void* const* d_in, const int* in_sizes, int n_in,
                              void* d_out, int out_size, void* d_ws, size_t ws_size,
                              hipStream_t stream) {
  (void)in_sizes; (void)n_in; (void)out_size; (void)ws_size;
  const float* x    = (const float*)d_in[0];
  const float* Wq   = (const float*)d_in[1];
  const float* Wkv  = (const float*)d_in[2];
  const float* Wlin = (const float*)d_in[3];
  const float* blin = (const float*)d_in[4];
  float* out = (float*)d_out;              // reference output dtype = float32

  // workspace layout (~160 MB total); staged operands fragment-major v2
  bf16* x_bf  = (bf16*)d_ws;                  // 33,554,432
  bf16* WTc   = x_bf + 33554432;              // 3,145,728   [Wq^T | Wkv^T] frag-v2
  bf16* WlinT = WTc + 3145728;                // 1,048,576   row-major (make_w2t)
  bf16* Yq    = WlinT + 1048576;              // 33,554,432  frag-v2
  bf16* W2T   = Yq + 33554432;                // 8,388,608   frag-v2
  float* ctxAcc = (float*)(W2T + 8388608);    // 128 * 4160 fp32 (R | Z)

  cast_x_frag<<<1024, 256, 0, stream>>>(x, x_bf);
  wcast_frag<<<dim3(4, 32), 256, 0, stream>>>(Wq, WTc, 1024, 0);
  wcast_frag<<<dim3(4, 64), 256, 0, stream>>>(Wkv, WTc, 2048, 1024);
  tcast<<<dim3(32, 32), dim3(32, 8), 0, stream>>>(Wlin, WlinT, 1024, 1024);

  hipMemsetAsync(ctxAcc, 0, (size_t)128 * 4160 * sizeof(float), stream);

  gemm_qkv<<<dim3(128 * QKV_NT), 512, 0, stream>>>(x_bf, WTc, Yq, ctxAcc);
  make_w2t<<<dim3(16, 128), 256, 0, stream>>>(ctxAcc, WlinT, W2T);
  gemm_out<<<dim3(512), 512, 0, stream>>>(Yq, W2T, out, blin);
}

// Round 13
// 370.199 us; speedup vs baseline: 1.1254x; 1.1254x over previous
//
#include <hip/hip_runtime.h>
#include <hip/hip_bf16.h>
#include <cstdint>

using bf16 = __hip_bfloat16;
typedef __attribute__((ext_vector_type(8))) short bf16x8;
typedef __attribute__((ext_vector_type(4))) float f32x4;

struct alignas(16) B8 { bf16 h[8]; };
struct alignas(8)  B4 { bf16 h[4]; };

__device__ __forceinline__ void gll16(const void* g, void* l) {
  __builtin_amdgcn_global_load_lds((__attribute__((address_space(1))) void*)g,
                                   (__attribute__((address_space(3))) void*)l,
                                   16, 0, 0);
}

// =================================================================================
// FRAGMENT-MAJOR GLOBAL LAYOUT: for a [rows][1024] operand, 16-B chunk id =
//   ((row>>4)*128 + (k>>3))*16 + (row&15)      (chunk content = 8 bf16 k-elems)
// Staging a 16-row group x 32-k section = 64 CONSECUTIVE chunks -> each gll16
// reads 1KB fully contiguous (perfect coalescing) and lands linearly in LDS in
// exactly fragment order -> frag ds_read_b128 = base + lane*16 (zero conflicts).
// =================================================================================

// ---------------- x fp32 [32768][1024] -> fragment-major bf16 ----------------
// (r13: global loads vectorized to float4; LDS bounce + drain unchanged)
__global__ __launch_bounds__(256) void cast_x_frag(const float* __restrict__ x,
                                                   bf16* __restrict__ xr) {
  __shared__ float tile[16][257];
  const int g = blockIdx.x;                    // 16-row group, 0..2047
  const int t = threadIdx.x;
  const float* src = x + (size_t)g * 16384;    // 16 rows * 1024
  bf16* dst = xr + (size_t)g * 16384;          // 2048 chunks * 8 elems
  const int r = t >> 4, cl = t & 15;
  for (int kp = 0; kp < 4; ++kp) {
    const int k0 = kp * 256;
    if (kp) __syncthreads();
    #pragma unroll
    for (int s = 0; s < 4; ++s) {              // 4 x float4 = 16 floats/thread;
      const int c0 = cl * 4 + 64 * s;          // 16 lanes = 256B contiguous
      float4 v = *(const float4*)(src + (size_t)r * 1024 + k0 + c0);
      tile[r][c0 + 0] = v.x; tile[r][c0 + 1] = v.y;
      tile[r][c0 + 2] = v.z; tile[r][c0 + 3] = v.w;
    }
    __syncthreads();
    #pragma unroll
    for (int rd = 0; rd < 2; ++rd) {
      const int c = rd * 256 + t;
      const int ql = c >> 4, rr = c & 15;      // bank = rr + 8q + jj: conflict-free
      B8 o;
      #pragma unroll
      for (int jj = 0; jj < 8; ++jj) o.h[jj] = __float2bfloat16(tile[rr][ql * 8 + jj]);
      *(B8*)(dst + ((size_t)(kp * 32 + ql) * 16 + rr) * 8) = o;   // contiguous stores
    }
  }
}

// ---------------- W fp32 [K][N] -> fragment-major bf16 of W^T ----------------
// out chunk = (((n_glob0+n)>>4)*128 + (k>>3))*16 + (n&15)
__global__ __launch_bounds__(256) void wcast_frag(const float* __restrict__ W,
                                                  bf16* __restrict__ out,
                                                  int N, int n_glob0) {
  __shared__ float tw[256][17];
  const int k0 = blockIdx.x * 256;
  const int n0 = blockIdx.y * 16;
  const int t = threadIdx.x;
  {
    const int nn = t & 15, kk0 = t >> 4;       // lanes 0..15: 64B contiguous per row
    #pragma unroll
    for (int s = 0; s < 16; ++s) {
      const int kk = kk0 + 16 * s;
      tw[kk][nn] = W[(size_t)(k0 + kk) * N + n0 + nn];
    }
  }
  __syncthreads();
  const int ng = (n_glob0 + n0) >> 4;
  #pragma unroll
  for (int rd = 0; rd < 2; ++rd) {
    const int c = rd * 256 + t;
    const int ql = c >> 4, r = c & 15;         // bank = 8q + 17jj + r: free
    B8 o;
    #pragma unroll
    for (int jj = 0; jj < 8; ++jj) o.h[jj] = __float2bfloat16(tw[ql * 8 + jj][r]);
    *(B8*)(out + (((size_t)ng * 128 + (k0 >> 3) + ql) * 16 + r) * 8) = o;
  }
}

// ---------------- transpose + cast: W[K][N] fp32 -> WT[N][K] bf16 (row-major) ----
__global__ void tcast(const float* __restrict__ W, bf16* __restrict__ WT, int K, int N) {
  __shared__ float tile[32][33];
  int k0 = blockIdx.y * 32, n0 = blockIdx.x * 32;
  int tx = threadIdx.x, ty = threadIdx.y;  // block (32,8)
  for (int yy = ty; yy < 32; yy += 8)
    tile[yy][tx] = W[(size_t)(k0 + yy) * N + n0 + tx];
  __syncthreads();
  for (int yy = ty; yy < 32; yy += 8)
    WT[(size_t)(n0 + yy) * K + k0 + tx] = __float2bfloat16(tile[tx][yy]);
}

// =================================================================================
// Shared 256x256-tile, BK=32-per-section, 8-wave pipelined main loop (K=1024).
// Fragment-major operands; zero-conflict frag reads. Staging gll16 ops are
// interleaved into the MFMA clusters; boundary = vmcnt(4) + s_barrier only.
// Section v consumes slot v&3, prefetches (v+1)&3, stages (v+3)&3 in-cluster.
// (r8 configuration — best measured: gemm_qkv 200.7 us, MfmaUtil 46.8%;
//  reproduced r11 at 200.5-201.8 us. 32x32x16 variant (r12) regressed to 233 —
//  do not revisit: fewer/longer MFMA ops under-hide the per-section memory ops.)
// =================================================================================
__device__ __forceinline__ void gemm_mainloop_256(
    const bf16* __restrict__ aop0, const bf16* __restrict__ aop1,
    const bf16* __restrict__ bop0, const bf16* __restrict__ bop1,
    bf16* ldsA, bf16* ldsB, int wd0, int wd1,
    int aoff, int boff, f32x4 (&acc)[8][4])
{
#define STAGE_A(slot, ko) do { gll16(aop0 + (ko) * 16, ldsA + (slot) * 8192 + wd0); \
                               gll16(aop1 + (ko) * 16, ldsA + (slot) * 8192 + wd1); } while (0)
#define STAGE_B(slot, ko) do { gll16(bop0 + (ko) * 16, ldsB + (slot) * 8192 + wd0); \
                               gll16(bop1 + (ko) * 16, ldsB + (slot) * 8192 + wd1); } while (0)
#define AFRAG(slot, i) (*(const bf16x8*)(ldsA + (slot) * 8192 + aoff + (i) * 512))
#define BFRAG(slot, j) (*(const bf16x8*)(ldsB + (slot) * 8192 + boff + (j) * 512))

  bf16x8 a1[4], a2[4], bb[2][4];

#define SECTION(S, CURB, NXTB, DO_PF, PFS, DO_ST, SLOT, KO)                         \
  do {                                                                              \
    asm volatile("s_waitcnt lgkmcnt(0)" ::: "memory");                              \
    __builtin_amdgcn_sched_barrier(0);                                              \
    __builtin_amdgcn_s_setprio(1);                                                  \
    _Pragma("unroll")                                                               \
    for (int i = 0; i < 4; i++) {                                                   \
      _Pragma("unroll")                                                             \
      for (int j = 0; j < 4; j++)                                                   \
        acc[i][j] = __builtin_amdgcn_mfma_f32_16x16x32_bf16(a1[i], bb[CURB][j],     \
                                                            acc[i][j], 0, 0, 0);    \
      a2[i] = AFRAG(S, i + 4);                                                      \
      if (DO_ST && i == 0) gll16(aop0 + (KO) * 16, ldsA + (SLOT) * 8192 + wd0);     \
      if (DO_ST && i == 1) gll16(aop1 + (KO) * 16, ldsA + (SLOT) * 8192 + wd1);     \
    }                                                                               \
    asm volatile("s_waitcnt lgkmcnt(0)" ::: "memory");                              \
    __builtin_amdgcn_sched_barrier(0);                                              \
    _Pragma("unroll")                                                               \
    for (int i = 0; i < 4; i++) {                                                   \
      _Pragma("unroll")                                                             \
      for (int j = 0; j < 4; j++)                                                   \
        acc[i + 4][j] = __builtin_amdgcn_mfma_f32_16x16x32_bf16(a2[i], bb[CURB][j], \
                                                                acc[i + 4][j], 0, 0, 0); \
      if (DO_PF) { bb[NXTB][i] = BFRAG(PFS, i); a1[i] = AFRAG(PFS, i); }            \
      if (DO_ST && i == 0) gll16(bop0 + (KO) * 16, ldsB + (SLOT) * 8192 + wd0);     \
      if (DO_ST && i == 1) gll16(bop1 + (KO) * 16, ldsB + (SLOT) * 8192 + wd1);     \
    }                                                                               \
    __builtin_amdgcn_s_setprio(0);                                                  \
  } while (0)

#define BOUNDARY(VMC)                                                               \
  do {                                                                              \
    asm volatile("s_waitcnt vmcnt(" #VMC ")" ::: "memory");                         \
    __builtin_amdgcn_s_barrier();                                                   \
    __builtin_amdgcn_sched_barrier(0);                                              \
  } while (0)

  // prologue: stage slots 0,1,2; retire 0,1 (slot 2 stays in flight = steady state)
  STAGE_A(0, 0);  STAGE_B(0, 0);
  STAGE_A(1, 32); STAGE_B(1, 32);
  STAGE_A(2, 64); STAGE_B(2, 64);
  asm volatile("s_waitcnt vmcnt(4)" ::: "memory");
  __builtin_amdgcn_s_barrier();
  __builtin_amdgcn_sched_barrier(0);
  #pragma unroll
  for (int j = 0; j < 4; j++) bb[0][j] = BFRAG(0, j);
  #pragma unroll
  for (int i = 0; i < 4; i++) a1[i] = AFRAG(0, i);

  // sections 0..27: section v consumes slot v&3, prefetches slot (v+1)&3,
  // stages slot (v+3)&3 at ko=(v+3)*32 inside its MFMA clusters.
  for (int q = 0; q < 7; ++q) {
    const int ko = q * 128;
    SECTION(0, 0, 1, true, 1, true, 3, ko + 96);
    BOUNDARY(4);
    SECTION(1, 1, 0, true, 2, true, 0, ko + 128);
    BOUNDARY(4);
    SECTION(2, 0, 1, true, 3, true, 1, ko + 160);
    BOUNDARY(4);
    SECTION(3, 1, 0, true, 0, true, 2, ko + 192);
    BOUNDARY(4);
  }
  // tail: v=28 (stages last chunk ko=992 -> slot 3), then drain
  SECTION(0, 0, 1, true, 1, true, 3, 992);
  BOUNDARY(4);
  SECTION(1, 1, 0, true, 2, false, 0, 0);
  BOUNDARY(0);
  SECTION(2, 0, 1, true, 3, false, 0, 0);
  BOUNDARY(0);
  SECTION(3, 1, 0, false, 0, false, 0, 0);

  __syncthreads();   // all frag reads done before epilogues reuse/overwrite LDS
#undef SECTION
#undef BOUNDARY
#undef STAGE_A
#undef STAGE_B
#undef AFRAG
#undef BFRAG
}

// =================================================================================
// Fused QKV GEMM:  T = x_bf @ [Wq | Wkv]  (M=32768, N=3072, K=1024)
//  - all operands fragment-major; XCD-chunked swizzle 1536 = 8 x 192 (bm-major).
//  - q tiles (bn<4): per-row softmax over the wave's 64-col head slice (* DH^-0.5);
//    Yq written FRAGMENT-MAJOR (consumed by gemm_out staging).
//  - kv tiles: 2 heads/block. exp(k), v -> swizzled LDS [64][256] via b64 writes;
//    Z from registers (shfl reduce); R[d][e] partial via MFMA; fp32 atomics.
// =================================================================================
constexpr int QKV_NT = 12;   // N/256

__global__ __launch_bounds__(512, 2)
void gemm_qkv(const bf16* __restrict__ A, const bf16* __restrict__ BT,
              bf16* __restrict__ Yq, float* __restrict__ ctxAcc)
{
  __shared__ __align__(16) union {
    struct { bf16 a[4 * 8192]; bf16 b[4 * 8192]; } g;       // 4+4 slots (16KB each)
    struct { bf16 ekT[2][16384]; bf16 vT[2][16384]; } c;    // kv epilogue (swizzled [64][256])
  } sm;

  const int t = threadIdx.x;
  const int wave = t >> 6, lane = t & 63;
  const int lr = lane & 15, kq = lane >> 4;
  const int wm = wave >> 2, wn = wave & 3;
  // XCD-chunked swizzle (bijective: 1536 = 8 * 192; dispatch round-robins bid%8)
  const int bid = (int)blockIdx.x;
  const int swz = (bid & 7) * 192 + (bid >> 3);
  const int bm = swz / QKV_NT, bn = swz % QKV_NT;
  const int m0 = bm * 256, n0 = bn * 256;

  // ---- staging pointers: wave stages 16-row group (m0>>4)+wave (+8 for aop1);
  //      lane sources chunk base + lane (1KB contiguous per gll16).
  const bf16* aop0 = A + (size_t)((m0 >> 4) + wave) * 16384 + lane * 8;
  const bf16* aop1 = aop0 + 131072;
  const bf16* bop0 = BT + (size_t)((n0 >> 4) + wave) * 16384 + lane * 8;
  const bf16* bop1 = bop0 + 131072;
  const int wd0 = wave * 512;          // elems, wave-uniform dest (gll writes base+lane*16)
  const int wd1 = 4096 + wave * 512;

  // ---- fragment-read offsets (contiguous 1KB per frag; lane*8 elems within)
  const int aoff = wm * 4096 + lane * 8;   // + i*512 per i-tile
  const int boff = wn * 2048 + lane * 8;   // + j*512 per j-tile

  const f32x4 zero = {0.f, 0.f, 0.f, 0.f};
  f32x4 acc[8][4];
  #pragma unroll
  for (int i = 0; i < 8; i++)
    #pragma unroll
    for (int j = 0; j < 4; j++) acc[i][j] = zero;

  gemm_mainloop_256(aop0, aop1, bop0, bop1, sm.g.a, sm.g.b, wd0, wd1,
                    aoff, boff, acc);

  if (bn < 4) {
    // ---- fused q softmax; Yq written fragment-major ----
    const int qb = (n0 + wn * 64) >> 3;
    const int jo = (lr >> 3) * 128;
    #pragma unroll
    for (int i = 0; i < 8; i++) {
      #pragma unroll
      for (int r = 0; r < 4; r++) {
        float m = fmaxf(fmaxf(acc[i][0][r], acc[i][1][r]),
                        fmaxf(acc[i][2][r], acc[i][3][r]));
        m = fmaxf(m, __shfl_xor(m, 1));
        m = fmaxf(m, __shfl_xor(m, 2));
        m = fmaxf(m, __shfl_xor(m, 4));
        m = fmaxf(m, __shfl_xor(m, 8));
        float ex[4]; float s = 0.f;
        #pragma unroll
        for (int j = 0; j < 4; j++) { ex[j] = __expf(acc[i][j][r] - m); s += ex[j]; }
        s += __shfl_xor(s, 1);
        s += __shfl_xor(s, 2);
        s += __shfl_xor(s, 4);
        s += __shfl_xor(s, 8);
        const float inv = 0.125f / s;           // scale = DH^-0.5
        const int row = m0 + wm * 128 + i * 16 + kq * 4 + r;
        bf16* yb = Yq + (((size_t)(row >> 4) * 128 + qb) * 16 + (row & 15)) * 8 + (lr & 7);
        #pragma unroll
        for (int j = 0; j < 4; j++)
          yb[j * 256 + jo] = __float2bfloat16(ex[j] * inv);
      }
    }
  } else {
    // ---- fused context: tile = 256 s-rows x 2 heads (each head: 64 k | 64 v) ----
    const int bb2 = m0 >> 12;                 // batch (4096 rows per batch)
    const int h0 = (n0 - 1024) >> 7;          // first head of this tile
    const int hloc = wn >> 1, isV = wn & 1;   // wave role
    bf16* const dstT = (isV ? sm.c.vT[hloc] : sm.c.ekT[hloc]);

    float zp[4] = {0.f, 0.f, 0.f, 0.f};
    #pragma unroll
    for (int i = 0; i < 8; i++) {
      const int sbase = wm * 128 + i * 16 + kq * 4;
      const int sxo = sbase >> 3;             // chunk (constant across r)
      const int sby = (sbase & 7) * 2;        // byte offset within chunk (0 or 8)
      #pragma unroll
      for (int j = 0; j < 4; j++) {
        const int d = j * 16 + lr;
        B4 pk;
        if (!isV) {
          #pragma unroll
          for (int r = 0; r < 4; r++) {
            float e = __expf(acc[i][j][r]);
            zp[j] += e;
            pk.h[r] = __float2bfloat16(e);
          }
        } else {
          #pragma unroll
          for (int r = 0; r < 4; r++) pk.h[r] = __float2bfloat16(acc[i][j][r]);
        }
        *(B4*)((char*)dstT + d * 512 + ((sxo ^ (d & 7)) << 4) + sby) = pk;
      }
    }

    if (!isV) {
      // Z[d] partial over this wave's 128 s-rows, straight from registers
      #pragma unroll
      for (int j = 0; j < 4; j++) {
        zp[j] += __shfl_xor(zp[j], 16);
        zp[j] += __shfl_xor(zp[j], 32);
      }
      if (kq == 0) {
        float* zb = ctxAcc + (size_t)(bb2 * 16 + h0 + hloc) * 4160 + 4096;
        #pragma unroll
        for (int j = 0; j < 4; j++) atomicAdd(zb + j * 16 + lr, zp[j]);
      }
    }
    __syncthreads();

    // R[d][e] partial via MFMA over K=256 s-rows; wave -> (head = wave>>2, d-quad = wave&3)
    const int hh = wave >> 2, dq = wave & 3;
    const bf16* const ek = sm.c.ekT[hh];
    const bf16* const vv = sm.c.vT[hh];
    f32x4 racc[4] = {zero, zero, zero, zero};
    #pragma unroll
    for (int ks = 0; ks < 8; ks++) {
      const int ch = ks * 4 + kq;
      bf16x8 af = *(const bf16x8*)((const char*)ek + (dq * 16 + lr) * 512 + ((ch ^ (lr & 7)) << 4));
      #pragma unroll
      for (int j = 0; j < 4; j++) {
        bf16x8 bfr = *(const bf16x8*)((const char*)vv + (j * 16 + lr) * 512 + ((ch ^ (lr & 7)) << 4));
        racc[j] = __builtin_amdgcn_mfma_f32_16x16x32_bf16(af, bfr, racc[j], 0, 0, 0);
      }
    }
    float* cb = ctxAcc + (size_t)(bb2 * 16 + h0 + hh) * 4160;
    #pragma unroll
    for (int j = 0; j < 4; j++) {
      #pragma unroll
      for (int r = 0; r < 4; r++)
        atomicAdd(cb + (dq * 16 + kq * 4 + r) * 64 + j * 16 + lr, racc[j][r]);
    }
  }
}

// ---------------- W2T[b] = (R/Z) @ WlinT-slice, written FRAGMENT-MAJOR ----------
__global__ __launch_bounds__(256) void make_w2t(const float* __restrict__ ctxAcc,
                                                const bf16* __restrict__ WlinT,
                                                bf16* __restrict__ W2T) {
  const int nc = blockIdx.x;      // 0..15
  const int bh = blockIdx.y;      // 0..127
  const int b = bh >> 4, h = bh & 15;
  const int t = threadIdx.x, lane = t & 63, w = t >> 6;
  const float* src = ctxAcc + (size_t)bh * 4160;
  const float invz = 1.0f / src[4096 + lane];   // Z[d], d = lane
  float creg[64];
  const float* crow = src + lane * 64;
  #pragma unroll
  for (int e4 = 0; e4 < 16; e4++) {
    float4 v = *(const float4*)(crow + e4 * 4);
    creg[e4 * 4 + 0] = v.x * invz; creg[e4 * 4 + 1] = v.y * invz;
    creg[e4 * 4 + 2] = v.z * invz; creg[e4 * 4 + 3] = v.w * invz;
  }
  for (int i = 0; i < 16; i++) {
    const int n = nc * 64 + w * 16 + i;
    const bf16* wrow = WlinT + (size_t)n * 1024 + h * 64;
    float acc = 0.f;
    #pragma unroll
    for (int e8 = 0; e8 < 8; e8++) {
      B8 v = *(const B8*)(wrow + e8 * 8);
      #pragma unroll
      for (int j = 0; j < 8; j++) acc += creg[e8 * 8 + j] * __bfloat162float(v.h[j]);
    }
    // fragment-major: col = h*64+lane -> q = h*8 + (lane>>3), e = lane&7
    W2T[(size_t)b * 1048576 +
        (((size_t)(n >> 4) * 128 + h * 8 + (lane >> 3)) * 16 + (n & 15)) * 8 + (lane & 7)]
        = __float2bfloat16(acc);
  }
}

// ---------------- out[b] = Yq[b] @ W2T[b]^T + blin, fp32 output -------------------
// per batch: M=4096, N=1024, K=1024; fragment-major operands; grid 512
// XCD-chunked swizzle: each XCD owns one batch (64 blocks): W2T[b] (2MB) L2-resident.
__global__ __launch_bounds__(512, 2)
void gemm_out(const bf16* __restrict__ Aall, const bf16* __restrict__ BTall,
              float* __restrict__ Call, const float* __restrict__ bias)
{
  __shared__ __align__(16) struct { bf16 a[4 * 8192]; bf16 b[4 * 8192]; } sm;
  const int t = threadIdx.x;
  const int wave = t >> 6, lane = t & 63;
  const int lr = lane & 15, kq = lane >> 4;
  const int wm = wave >> 2, wn = wave & 3;
  // bijective XCD swizzle: 512 = 8 * 64; XCD x -> batch x
  const int bid = (int)blockIdx.x;
  const int swz = (bid & 7) * 64 + (bid >> 3);
  const int bz = swz >> 6;
  const int r  = swz & 63;
  const int bm = r >> 2, bn = r & 3;
  const int m0 = bm * 256, n0 = bn * 256;
  const bf16* A  = Aall  + (size_t)bz * 4194304;
  const bf16* BT = BTall + (size_t)bz * 1048576;
  float* C       = Call  + (size_t)bz * 4194304;

  const bf16* aop0 = A + (size_t)((m0 >> 4) + wave) * 16384 + lane * 8;
  const bf16* aop1 = aop0 + 131072;
  const bf16* bop0 = BT + (size_t)((n0 >> 4) + wave) * 16384 + lane * 8;
  const bf16* bop1 = bop0 + 131072;
  const int wd0 = wave * 512;
  const int wd1 = 4096 + wave * 512;

  const int aoff = wm * 4096 + lane * 8;
  const int boff = wn * 2048 + lane * 8;

  const f32x4 zero = {0.f, 0.f, 0.f, 0.f};
  f32x4 acc[8][4];
  #pragma unroll
  for (int i = 0; i < 8; i++)
    #pragma unroll
    for (int j = 0; j < 4; j++) acc[i][j] = zero;

  gemm_mainloop_256(aop0, aop1, bop0, bop1, sm.a, sm.b, wd0, wd1,
                    aoff, boff, acc);

  float bv[4];
  #pragma unroll
  for (int j = 0; j < 4; j++) bv[j] = bias[n0 + wn * 64 + j * 16 + lr];
  #pragma unroll
  for (int i = 0; i < 8; i++) {
    const int row0 = m0 + wm * 128 + i * 16 + kq * 4;
    #pragma unroll
    for (int j = 0; j < 4; j++) {
      const int col = n0 + wn * 64 + j * 16 + lr;
      const float bvj = bv[j];
      #pragma unroll
      for (int r2 = 0; r2 < 4; r2++)
        C[(size_t)(row0 + r2) * 1024 + col] = acc[i][j][r2] + bvj;
    }
  }
}

// ---------------------------------------------------------------------------------
extern "C" void kernel_launch(void* const* d_in, const int* in_sizes, int n_in,
                              void* d_out, int out_size, void* d_ws, size_t ws_size,
                              hipStream_t stream) {
  (void)in_sizes; (void)n_in; (void)out_size; (void)ws_size;
  const float* x    = (const float*)d_in[0];
  const float* Wq   = (const float*)d_in[1];
  const float* Wkv  = (const float*)d_in[2];
  const float* Wlin = (const float*)d_in[3];
  const float* blin = (const float*)d_in[4];
  float* out = (float*)d_out;              // reference output dtype = float32

  // workspace layout (~160 MB total); all staged operands fragment-major
  bf16* x_bf  = (bf16*)d_ws;                  // 33,554,432
  bf16* WTc   = x_bf + 33554432;              // 3,145,728   [Wq^T | Wkv^T] frag-major
  bf16* WlinT = WTc + 3145728;                // 1,048,576   row-major (make_w2t)
  bf16* Yq    = WlinT + 1048576;              // 33,554,432  frag-major
  bf16* W2T   = Yq + 33554432;                // 8,388,608   frag-major
  float* ctxAcc = (float*)(W2T + 8388608);    // 128 * 4160 fp32 (R | Z)

  cast_x_frag<<<2048, 256, 0, stream>>>(x, x_bf);
  wcast_frag<<<dim3(4, 64), 256, 0, stream>>>(Wq, WTc, 1024, 0);
  wcast_frag<<<dim3(4, 128), 256, 0, stream>>>(Wkv, WTc, 2048, 1024);
  tcast<<<dim3(32, 32), dim3(32, 8), 0, stream>>>(Wlin, WlinT, 1024, 1024);

  hipMemsetAsync(ctxAcc, 0, (size_t)128 * 4160 * sizeof(float), stream);

  gemm_qkv<<<dim3(128 * QKV_NT), 512, 0, stream>>>(x_bf, WTc, Yq, ctxAcc);
  make_w2t<<<dim3(16, 128), 256, 0, stream>>>(ctxAcc, WlinT, W2T);
  gemm_out<<<dim3(512), 512, 0, stream>>>(Yq, W2T, out, blin);
}

// Round 14
// 368.229 us; speedup vs baseline: 1.1314x; 1.0054x over previous
//
#include <hip/hip_runtime.h>
#include <hip/hip_bf16.h>
#include <cstdint>

using bf16 = __hip_bfloat16;
typedef __attribute__((ext_vector_type(8))) short bf16x8;
typedef __attribute__((ext_vector_type(4))) float f32x4;

struct alignas(16) B8 { bf16 h[8]; };
struct alignas(8)  B4 { bf16 h[4]; };

__device__ __forceinline__ void gll16(const void* g, void* l) {
  __builtin_amdgcn_global_load_lds((__attribute__((address_space(1))) void*)g,
                                   (__attribute__((address_space(3))) void*)l,
                                   16, 0, 0);
}

// =================================================================================
// FRAGMENT-MAJOR GLOBAL LAYOUT: for a [rows][1024] operand, 16-B chunk id =
//   ((row>>4)*128 + (k>>3))*16 + (row&15)      (chunk content = 8 bf16 k-elems)
// A-staging: 16-row group x 32-k section = 64 consecutive chunks -> each gll16
// reads 1KB contiguous into linear LDS in fragment order (conflict-free reads).
// B-OPERAND (r14): read DIRECTLY global->VGPR (no LDS staging) — per-lane
// dwordx4, fully coalesced, L2-resident panel. Cuts per-section LDS traffic 31%.
// =================================================================================

// ---------------- x fp32 [32768][1024] -> fragment-major bf16 ----------------
__global__ __launch_bounds__(256) void cast_x_frag(const float* __restrict__ x,
                                                   bf16* __restrict__ xr) {
  __shared__ float tile[16][257];
  const int g = blockIdx.x;                    // 16-row group, 0..2047
  const int t = threadIdx.x;
  const float* src = x + (size_t)g * 16384;    // 16 rows * 1024
  bf16* dst = xr + (size_t)g * 16384;          // 2048 chunks * 8 elems
  const int r = t >> 4, cl = t & 15;
  for (int kp = 0; kp < 4; ++kp) {
    const int k0 = kp * 256;
    if (kp) __syncthreads();
    #pragma unroll
    for (int s = 0; s < 4; ++s) {              // 4 x float4 = 16 floats/thread
      const int c0 = cl * 4 + 64 * s;
      float4 v = *(const float4*)(src + (size_t)r * 1024 + k0 + c0);
      tile[r][c0 + 0] = v.x; tile[r][c0 + 1] = v.y;
      tile[r][c0 + 2] = v.z; tile[r][c0 + 3] = v.w;
    }
    __syncthreads();
    #pragma unroll
    for (int rd = 0; rd < 2; ++rd) {
      const int c = rd * 256 + t;
      const int ql = c >> 4, rr = c & 15;      // bank = rr + 8q + jj: conflict-free
      B8 o;
      #pragma unroll
      for (int jj = 0; jj < 8; ++jj) o.h[jj] = __float2bfloat16(tile[rr][ql * 8 + jj]);
      *(B8*)(dst + ((size_t)(kp * 32 + ql) * 16 + rr) * 8) = o;   // contiguous stores
    }
  }
}

// ---------------- W fp32 [K][N] -> fragment-major bf16 of W^T ----------------
__global__ __launch_bounds__(256) void wcast_frag(const float* __restrict__ W,
                                                  bf16* __restrict__ out,
                                                  int N, int n_glob0) {
  __shared__ float tw[256][17];
  const int k0 = blockIdx.x * 256;
  const int n0 = blockIdx.y * 16;
  const int t = threadIdx.x;
  {
    const int nn = t & 15, kk0 = t >> 4;       // lanes 0..15: 64B contiguous per row
    #pragma unroll
    for (int s = 0; s < 16; ++s) {
      const int kk = kk0 + 16 * s;
      tw[kk][nn] = W[(size_t)(k0 + kk) * N + n0 + nn];
    }
  }
  __syncthreads();
  const int ng = (n_glob0 + n0) >> 4;
  #pragma unroll
  for (int rd = 0; rd < 2; ++rd) {
    const int c = rd * 256 + t;
    const int ql = c >> 4, r = c & 15;         // bank = 8q + 17jj + r: free
    B8 o;
    #pragma unroll
    for (int jj = 0; jj < 8; ++jj) o.h[jj] = __float2bfloat16(tw[ql * 8 + jj][r]);
    *(B8*)(out + (((size_t)ng * 128 + (k0 >> 3) + ql) * 16 + r) * 8) = o;
  }
}

// ---------------- transpose + cast: W[K][N] fp32 -> WT[N][K] bf16 (row-major) ----
__global__ void tcast(const float* __restrict__ W, bf16* __restrict__ WT, int K, int N) {
  __shared__ float tile[32][33];
  int k0 = blockIdx.y * 32, n0 = blockIdx.x * 32;
  int tx = threadIdx.x, ty = threadIdx.y;  // block (32,8)
  for (int yy = ty; yy < 32; yy += 8)
    tile[yy][tx] = W[(size_t)(k0 + yy) * N + n0 + tx];
  __syncthreads();
  for (int yy = ty; yy < 32; yy += 8)
    WT[(size_t)(n0 + yy) * K + k0 + tx] = __float2bfloat16(tile[tx][yy]);
}

// =================================================================================
// 256x256-tile, BK=32/section, 8-wave main loop (K=1024, 32 sections).  r14:
// A staged via gll16 (ring of 4 x 16KB slots, 3 ahead, 2 gll16/section/wave);
// B read DIRECTLY global->bb[2][4] regs: section v loads bb[(v+1)&1] in cluster 1
// (used next section; ~1 section of latency budget >> HBM latency; compiler
// inserts the register-dependency vmcnt — drain-of-old ops, near-free).
// Boundary = vmcnt(6) + s_barrier (6 VMEM/wave/section = 2 gll16 + 4 B-loads;
// <=6-newest window guarantees A(v+1)'s stage retired — the one thing the
// compiler can't track). LDS traffic/section-CU: 104 -> 72 KB (-31%).
// =================================================================================
__device__ __forceinline__ void gemm_mainloop_256(
    const bf16* __restrict__ aop0, const bf16* __restrict__ aop1,
    const bf16* __restrict__ bfp,
    bf16* ldsA, int wd0, int wd1, int aoff, f32x4 (&acc)[8][4])
{
#define STAGE_A(slot, ko) do { gll16(aop0 + (ko) * 16, ldsA + (slot) * 8192 + wd0); \
                               gll16(aop1 + (ko) * 16, ldsA + (slot) * 8192 + wd1); } while (0)
#define AFRAG(slot, i) (*(const bf16x8*)(ldsA + (slot) * 8192 + aoff + (i) * 512))
#define BGLOB(j, ko) (*(const bf16x8*)(bfp + (size_t)(j) * 16384 + (ko) * 16))

  bf16x8 a1[4], a2[4], bb[2][4];

#define SECTION(S, CURB, NXTB, DO_PFB, BKO, DO_PF, PFS, DO_ST, SLOT, KO)            \
  do {                                                                              \
    asm volatile("s_waitcnt lgkmcnt(0)" ::: "memory");                              \
    __builtin_amdgcn_sched_barrier(0);                                              \
    __builtin_amdgcn_s_setprio(1);                                                  \
    _Pragma("unroll")                                                               \
    for (int i = 0; i < 4; i++) {                                                   \
      _Pragma("unroll")                                                             \
      for (int j = 0; j < 4; j++)                                                   \
        acc[i][j] = __builtin_amdgcn_mfma_f32_16x16x32_bf16(a1[i], bb[CURB][j],     \
                                                            acc[i][j], 0, 0, 0);    \
      a2[i] = AFRAG(S, i + 4);                                                      \
      if (DO_ST && i == 0) gll16(aop0 + (KO) * 16, ldsA + (SLOT) * 8192 + wd0);     \
      if (DO_ST && i == 1) gll16(aop1 + (KO) * 16, ldsA + (SLOT) * 8192 + wd1);     \
      if (DO_PFB) bb[NXTB][i] = BGLOB(i, BKO);                                      \
    }                                                                               \
    asm volatile("s_waitcnt lgkmcnt(0)" ::: "memory");                              \
    __builtin_amdgcn_sched_barrier(0);                                              \
    _Pragma("unroll")                                                               \
    for (int i = 0; i < 4; i++) {                                                   \
      _Pragma("unroll")                                                             \
      for (int j = 0; j < 4; j++)                                                   \
        acc[i + 4][j] = __builtin_amdgcn_mfma_f32_16x16x32_bf16(a2[i], bb[CURB][j], \
                                                                acc[i + 4][j], 0, 0, 0); \
      if (DO_PF) { a1[i] = AFRAG(PFS, i); }                                         \
    }                                                                               \
    __builtin_amdgcn_s_setprio(0);                                                  \
  } while (0)

#define BOUNDARY(VMC)                                                               \
  do {                                                                              \
    asm volatile("s_waitcnt vmcnt(" #VMC ")" ::: "memory");                         \
    __builtin_amdgcn_s_barrier();                                                   \
    __builtin_amdgcn_sched_barrier(0);                                              \
  } while (0)

  // prologue: stage A slots 0,1,2 (6 gll16); load bb[0] = B(section 0).
  STAGE_A(0, 0); STAGE_A(1, 32); STAGE_A(2, 64);
  #pragma unroll
  for (int j = 0; j < 4; j++) bb[0][j] = BGLOB(j, 0);
  asm volatile("s_waitcnt vmcnt(4)" ::: "memory");   // retire all gll16 (B newest 4)
  __builtin_amdgcn_s_barrier();
  __builtin_amdgcn_sched_barrier(0);
  #pragma unroll
  for (int i = 0; i < 4; i++) a1[i] = AFRAG(0, i);

  // sections 0..27: consume A-slot v&3 / bb[v&1]; load bb[(v+1)&1] at BKO=(v+1)*32;
  // stage A-slot (v+3)&3 at KO=(v+3)*32.
  for (int q = 0; q < 7; ++q) {
    const int ko = q * 128;
    SECTION(0, 0, 1, true, ko + 32,  true, 1, true, 3, ko + 96);
    BOUNDARY(6);
    SECTION(1, 1, 0, true, ko + 64,  true, 2, true, 0, ko + 128);
    BOUNDARY(6);
    SECTION(2, 0, 1, true, ko + 96,  true, 3, true, 1, ko + 160);
    BOUNDARY(6);
    SECTION(3, 1, 0, true, ko + 128, true, 0, true, 2, ko + 192);
    BOUNDARY(6);
  }
  // tail: v=28 (last A stage, ko=992), then drain
  SECTION(0, 0, 1, true, 928, true, 1, true, 3, 992);
  BOUNDARY(6);
  SECTION(1, 1, 0, true, 960, true, 2, false, 0, 0);
  BOUNDARY(6);
  SECTION(2, 0, 1, true, 992, true, 3, false, 0, 0);
  BOUNDARY(6);
  SECTION(3, 1, 0, false, 0, false, 0, false, 0, 0);

  asm volatile("s_waitcnt vmcnt(0)" ::: "memory");
  __syncthreads();   // all frag reads/stages done before epilogues reuse LDS
#undef SECTION
#undef BOUNDARY
#undef STAGE_A
#undef AFRAG
#undef BGLOB
}

// =================================================================================
// Fused QKV GEMM:  T = x_bf @ [Wq | Wkv]  (M=32768, N=3072, K=1024)
//  - operands fragment-major; XCD-chunked swizzle 1536 = 8 x 192 (bm-major).
//  - q tiles (bn<4): per-row softmax over the wave's 64-col head slice (* DH^-0.5);
//    Yq written FRAGMENT-MAJOR (consumed by gemm_out staging).
//  - kv tiles: 2 heads/block. exp(k), v -> swizzled LDS [64][256] via b64 writes;
//    Z from registers (shfl reduce); R[d][e] partial via MFMA; fp32 atomics.
// =================================================================================
constexpr int QKV_NT = 12;   // N/256

__global__ __launch_bounds__(512, 2)
void gemm_qkv(const bf16* __restrict__ A, const bf16* __restrict__ BT,
              bf16* __restrict__ Yq, float* __restrict__ ctxAcc)
{
  __shared__ __align__(16) union {
    struct { bf16 a[4 * 8192]; } g;                         // A ring (64KB)
    struct { bf16 ekT[2][16384]; bf16 vT[2][16384]; } c;    // kv epilogue (128KB)
  } sm;

  const int t = threadIdx.x;
  const int wave = t >> 6, lane = t & 63;
  const int lr = lane & 15, kq = lane >> 4;
  const int wm = wave >> 2, wn = wave & 3;
  // XCD-chunked swizzle (bijective: 1536 = 8 * 192; dispatch round-robins bid%8)
  const int bid = (int)blockIdx.x;
  const int swz = (bid & 7) * 192 + (bid >> 3);
  const int bm = swz / QKV_NT, bn = swz % QKV_NT;
  const int m0 = bm * 256, n0 = bn * 256;

  // A staging: wave stages 16-row group (m0>>4)+wave (+8 for aop1), 1KB/gll16
  const bf16* aop0 = A + (size_t)((m0 >> 4) + wave) * 16384 + lane * 8;
  const bf16* aop1 = aop0 + 131072;
  // B direct: wave wn owns row-groups wn*4 .. wn*4+3 of the B panel
  const bf16* bfp = BT + (size_t)((n0 >> 4) + wn * 4) * 16384 + lane * 8;
  const int wd0 = wave * 512;          // elems; gll16 writes base + lane*16B
  const int wd1 = 4096 + wave * 512;
  const int aoff = wm * 4096 + lane * 8;   // + i*512 per i-tile

  const f32x4 zero = {0.f, 0.f, 0.f, 0.f};
  f32x4 acc[8][4];
  #pragma unroll
  for (int i = 0; i < 8; i++)
    #pragma unroll
    for (int j = 0; j < 4; j++) acc[i][j] = zero;

  gemm_mainloop_256(aop0, aop1, bfp, sm.g.a, wd0, wd1, aoff, acc);

  if (bn < 4) {
    // ---- fused q softmax; Yq written fragment-major ----
    const int qb = (n0 + wn * 64) >> 3;
    const int jo = (lr >> 3) * 128;
    #pragma unroll
    for (int i = 0; i < 8; i++) {
      #pragma unroll
      for (int r = 0; r < 4; r++) {
        float m = fmaxf(fmaxf(acc[i][0][r], acc[i][1][r]),
                        fmaxf(acc[i][2][r], acc[i][3][r]));
        m = fmaxf(m, __shfl_xor(m, 1));
        m = fmaxf(m, __shfl_xor(m, 2));
        m = fmaxf(m, __shfl_xor(m, 4));
        m = fmaxf(m, __shfl_xor(m, 8));
        float ex[4]; float s = 0.f;
        #pragma unroll
        for (int j = 0; j < 4; j++) { ex[j] = __expf(acc[i][j][r] - m); s += ex[j]; }
        s += __shfl_xor(s, 1);
        s += __shfl_xor(s, 2);
        s += __shfl_xor(s, 4);
        s += __shfl_xor(s, 8);
        const float inv = 0.125f / s;           // scale = DH^-0.5
        const int row = m0 + wm * 128 + i * 16 + kq * 4 + r;
        bf16* yb = Yq + (((size_t)(row >> 4) * 128 + qb) * 16 + (row & 15)) * 8 + (lr & 7);
        #pragma unroll
        for (int j = 0; j < 4; j++)
          yb[j * 256 + jo] = __float2bfloat16(ex[j] * inv);
      }
    }
  } else {
    // ---- fused context: tile = 256 s-rows x 2 heads (each head: 64 k | 64 v) ----
    const int bb2 = m0 >> 12;                 // batch (4096 rows per batch)
    const int h0 = (n0 - 1024) >> 7;          // first head of this tile
    const int hloc = wn >> 1, isV = wn & 1;   // wave role
    bf16* const dstT = (isV ? sm.c.vT[hloc] : sm.c.ekT[hloc]);

    float zp[4] = {0.f, 0.f, 0.f, 0.f};
    #pragma unroll
    for (int i = 0; i < 8; i++) {
      const int sbase = wm * 128 + i * 16 + kq * 4;
      const int sxo = sbase >> 3;             // chunk (constant across r)
      const int sby = (sbase & 7) * 2;        // byte offset within chunk (0 or 8)
      #pragma unroll
      for (int j = 0; j < 4; j++) {
        const int d = j * 16 + lr;
        B4 pk;
        if (!isV) {
          #pragma unroll
          for (int r = 0; r < 4; r++) {
            float e = __expf(acc[i][j][r]);
            zp[j] += e;
            pk.h[r] = __float2bfloat16(e);
          }
        } else {
          #pragma unroll
          for (int r = 0; r < 4; r++) pk.h[r] = __float2bfloat16(acc[i][j][r]);
        }
        *(B4*)((char*)dstT + d * 512 + ((sxo ^ (d & 7)) << 4) + sby) = pk;
      }
    }

    if (!isV) {
      // Z[d] partial over this wave's 128 s-rows, straight from registers
      #pragma unroll
      for (int j = 0; j < 4; j++) {
        zp[j] += __shfl_xor(zp[j], 16);
        zp[j] += __shfl_xor(zp[j], 32);
      }
      if (kq == 0) {
        float* zb = ctxAcc + (size_t)(bb2 * 16 + h0 + hloc) * 4160 + 4096;
        #pragma unroll
        for (int j = 0; j < 4; j++) atomicAdd(zb + j * 16 + lr, zp[j]);
      }
    }
    __syncthreads();

    // R[d][e] partial via MFMA over K=256 s-rows; wave -> (head = wave>>2, d-quad = wave&3)
    const int hh = wave >> 2, dq = wave & 3;
    const bf16* const ek = sm.c.ekT[hh];
    const bf16* const vv = sm.c.vT[hh];
    f32x4 racc[4] = {zero, zero, zero, zero};
    #pragma unroll
    for (int ks = 0; ks < 8; ks++) {
      const int ch = ks * 4 + kq;
      bf16x8 af = *(const bf16x8*)((const char*)ek + (dq * 16 + lr) * 512 + ((ch ^ (lr & 7)) << 4));
      #pragma unroll
      for (int j = 0; j < 4; j++) {
        bf16x8 bfr = *(const bf16x8*)((const char*)vv + (j * 16 + lr) * 512 + ((ch ^ (lr & 7)) << 4));
        racc[j] = __builtin_amdgcn_mfma_f32_16x16x32_bf16(af, bfr, racc[j], 0, 0, 0);
      }
    }
    float* cb = ctxAcc + (size_t)(bb2 * 16 + h0 + hh) * 4160;
    #pragma unroll
    for (int j = 0; j < 4; j++) {
      #pragma unroll
      for (int r = 0; r < 4; r++)
        atomicAdd(cb + (dq * 16 + kq * 4 + r) * 64 + j * 16 + lr, racc[j][r]);
    }
  }
}

// ---------------- W2T[b] = (R/Z) @ WlinT-slice, written FRAGMENT-MAJOR ----------
__global__ __launch_bounds__(256) void make_w2t(const float* __restrict__ ctxAcc,
                                                const bf16* __restrict__ WlinT,
                                                bf16* __restrict__ W2T) {
  const int nc = blockIdx.x;      // 0..15
  const int bh = blockIdx.y;      // 0..127
  const int b = bh >> 4, h = bh & 15;
  const int t = threadIdx.x, lane = t & 63, w = t >> 6;
  const float* src = ctxAcc + (size_t)bh * 4160;
  const float invz = 1.0f / src[4096 + lane];   // Z[d], d = lane
  float creg[64];
  const float* crow = src + lane * 64;
  #pragma unroll
  for (int e4 = 0; e4 < 16; e4++) {
    float4 v = *(const float4*)(crow + e4 * 4);
    creg[e4 * 4 + 0] = v.x * invz; creg[e4 * 4 + 1] = v.y * invz;
    creg[e4 * 4 + 2] = v.z * invz; creg[e4 * 4 + 3] = v.w * invz;
  }
  for (int i = 0; i < 16; i++) {
    const int n = nc * 64 + w * 16 + i;
    const bf16* wrow = WlinT + (size_t)n * 1024 + h * 64;
    float acc = 0.f;
    #pragma unroll
    for (int e8 = 0; e8 < 8; e8++) {
      B8 v = *(const B8*)(wrow + e8 * 8);
      #pragma unroll
      for (int j = 0; j < 8; j++) acc += creg[e8 * 8 + j] * __bfloat162float(v.h[j]);
    }
    // fragment-major: col = h*64+lane -> q = h*8 + (lane>>3), e = lane&7
    W2T[(size_t)b * 1048576 +
        (((size_t)(n >> 4) * 128 + h * 8 + (lane >> 3)) * 16 + (n & 15)) * 8 + (lane & 7)]
        = __float2bfloat16(acc);
  }
}

// ---------------- out[b] = Yq[b] @ W2T[b]^T + blin, fp32 output -------------------
// per batch: M=4096, N=1024, K=1024; fragment-major operands; grid 512
// XCD-chunked swizzle: each XCD owns one batch (W2T[b] 2MB L2-resident).
__global__ __launch_bounds__(512, 2)
void gemm_out(const bf16* __restrict__ Aall, const bf16* __restrict__ BTall,
              float* __restrict__ Call, const float* __restrict__ bias)
{
  __shared__ __align__(16) struct { bf16 a[4 * 8192]; } sm;
  const int t = threadIdx.x;
  const int wave = t >> 6, lane = t & 63;
  const int lr = lane & 15, kq = lane >> 4;
  const int wm = wave >> 2, wn = wave & 3;
  // bijective XCD swizzle: 512 = 8 * 64; XCD x -> batch x
  const int bid = (int)blockIdx.x;
  const int swz = (bid & 7) * 64 + (bid >> 3);
  const int bz = swz >> 6;
  const int r  = swz & 63;
  const int bm = r >> 2, bn = r & 3;
  const int m0 = bm * 256, n0 = bn * 256;
  const bf16* A  = Aall  + (size_t)bz * 4194304;
  const bf16* BT = BTall + (size_t)bz * 1048576;
  float* C       = Call  + (size_t)bz * 4194304;

  const bf16* aop0 = A + (size_t)((m0 >> 4) + wave) * 16384 + lane * 8;
  const bf16* aop1 = aop0 + 131072;
  const bf16* bfp = BT + (size_t)((n0 >> 4) + wn * 4) * 16384 + lane * 8;
  const int wd0 = wave * 512;
  const int wd1 = 4096 + wave * 512;
  const int aoff = wm * 4096 + lane * 8;

  const f32x4 zero = {0.f, 0.f, 0.f, 0.f};
  f32x4 acc[8][4];
  #pragma unroll
  for (int i = 0; i < 8; i++)
    #pragma unroll
    for (int j = 0; j < 4; j++) acc[i][j] = zero;

  gemm_mainloop_256(aop0, aop1, bfp, sm.a, wd0, wd1, aoff, acc);

  float bv[4];
  #pragma unroll
  for (int j = 0; j < 4; j++) bv[j] = bias[n0 + wn * 64 + j * 16 + lr];
  #pragma unroll
  for (int i = 0; i < 8; i++) {
    const int row0 = m0 + wm * 128 + i * 16 + kq * 4;
    #pragma unroll
    for (int j = 0; j < 4; j++) {
      const int col = n0 + wn * 64 + j * 16 + lr;
      const float bvj = bv[j];
      #pragma unroll
      for (int r2 = 0; r2 < 4; r2++)
        C[(size_t)(row0 + r2) * 1024 + col] = acc[i][j][r2] + bvj;
    }
  }
}

// ---------------------------------------------------------------------------------
extern "C" void kernel_launch(void* const* d_in, const int* in_sizes, int n_in,
                              void* d_out, int out_size, void* d_ws, size_t ws_size,
                              hipStream_t stream) {
  (void)in_sizes; (void)n_in; (void)out_size; (void)ws_size;
  const float* x    = (const float*)d_in[0];
  const float* Wq   = (const float*)d_in[1];
  const float* Wkv  = (const float*)d_in[2];
  const float* Wlin = (const float*)d_in[3];
  const float* blin = (const float*)d_in[4];
  float* out = (float*)d_out;              // reference output dtype = float32

  // workspace layout (~160 MB total); all staged operands fragment-major
  bf16* x_bf  = (bf16*)d_ws;                  // 33,554,432
  bf16* WTc   = x_bf + 33554432;              // 3,145,728   [Wq^T | Wkv^T] frag-major
  bf16* WlinT = WTc + 3145728;                // 1,048,576   row-major (make_w2t)
  bf16* Yq    = WlinT + 1048576;              // 33,554,432  frag-major
  bf16* W2T   = Yq + 33554432;                // 8,388,608   frag-major
  float* ctxAcc = (float*)(W2T + 8388608);    // 128 * 4160 fp32 (R | Z)

  cast_x_frag<<<2048, 256, 0, stream>>>(x, x_bf);
  wcast_frag<<<dim3(4, 64), 256, 0, stream>>>(Wq, WTc, 1024, 0);
  wcast_frag<<<dim3(4, 128), 256, 0, stream>>>(Wkv, WTc, 2048, 1024);
  tcast<<<dim3(32, 32), dim3(32, 8), 0, stream>>>(Wlin, WlinT, 1024, 1024);

  hipMemsetAsync(ctxAcc, 0, (size_t)128 * 4160 * sizeof(float), stream);

  gemm_qkv<<<dim3(128 * QKV_NT), 512, 0, stream>>>(x_bf, WTc, Yq, ctxAcc);
  make_w2t<<<dim3(16, 128), 256, 0, stream>>>(ctxAcc, WlinT, W2T);
  gemm_out<<<dim3(512), 512, 0, stream>>>(Yq, W2T, out, blin);
}